// Round 22
// baseline (148.987 us; speedup 1.0000x reference)
//
#include <hip/hip_runtime.h>
#include <math.h>

#define NTOK   16384
#define DIM    2048
#define NEXP   64
#define TOPK   8
#define TB     16          // tokens per block -> grid 1024
#define KC     64          // K chunk
#define NCHUNK (DIM / KC)  // 32
#define NLIMB  4

typedef int    v4i __attribute__((ext_vector_type(4)));
typedef double v4d __attribute__((ext_vector_type(4)));

// ws layout: [0,512) pinv (64 f64); [512, 512+524288) proto limb dwords
#define WS_NEEDED (512 + (size_t)NEXP * NLIMB * (DIM / 4) * 4)

#define XSCALE 134217728.0f     // 2^27 : x digits; residual <= 2^-28
#define PSCALE 8589934592.0f    // 2^33 : p digits; residual <= 2^-34
#define BIAS   0x80808080u     // per-byte +128 bias (carry-free digits)

// class-combine weights 2^(8d-60), d=0..6
__device__ __constant__ double CWD4[7] = {
    8.673617379884035e-19, 2.220446049250313e-16, 5.684341886080802e-14,
    1.4551915228366852e-11, 3.725290298461914e-09, 9.5367431640625e-07,
    2.44140625e-04};

// ---------------- pre-kernel: pinv (f64) + proto 4-limb radix-256 decomposition ----------------
__global__ __launch_bounds__(64) void proto_prep_kernel(
    const float* __restrict__ proto, double* __restrict__ pinv,
    int* __restrict__ plimb)
{
    const int e = blockIdx.x, t = threadIdx.x;
    const float* row = proto + (size_t)e * DIM;
    const int k0 = t * 32;
    double s = 0.0;
#pragma unroll
    for (int g = 0; g < 8; ++g) {
        unsigned pk0 = 0, pk1 = 0, pk2 = 0, pk3 = 0;
#pragma unroll
        for (int b = 0; b < 4; ++b) {
            float f = row[k0 + g * 4 + b];
            s += (double)f * (double)f;
            int u = (int)rintf(f * PSCALE);       // exact: pow2 scale + rndne
            unsigned ub = (unsigned)u + BIAS;     // carry-free biased digits
            pk0 |= ( ub        & 255u) << (8 * b);
            pk1 |= ((ub >>  8) & 255u) << (8 * b);
            pk2 |= ((ub >> 16) & 255u) << (8 * b);
            pk3 |= ( ub >> 24        ) << (8 * b);
        }
        const int dw = (k0 + g * 4) >> 2;
        plimb[(e * NLIMB + 0) * (DIM / 4) + dw] = (int)(pk0 ^ BIAS);
        plimb[(e * NLIMB + 1) * (DIM / 4) + dw] = (int)(pk1 ^ BIAS);
        plimb[(e * NLIMB + 2) * (DIM / 4) + dw] = (int)(pk2 ^ BIAS);
        plimb[(e * NLIMB + 3) * (DIM / 4) + dw] = (int)(pk3 ^ BIAS);
    }
#pragma unroll
    for (int d = 1; d < 64; d <<= 1)
        s += __shfl_xor(s, d, 64);
    if (t == 0)
        pinv[e] = 1.0 / fmax(sqrt(s), 1e-12);
}

#define MF(A, B, C) __builtin_amdgcn_mfma_i32_16x16x64_i8(A, B, C, 0, 0, 0)

// 16 class MFMAs (4x4 limbs, class d=i+j in 0..6), j-major (r18-verified)
#define BURST16(AF, B0, B1, B2, B3) do {                                                \
    acc[0]=MF(AF[0],B0,acc[0]); acc[1]=MF(AF[1],B0,acc[1]);                             \
    acc[2]=MF(AF[2],B0,acc[2]); acc[3]=MF(AF[3],B0,acc[3]);                             \
    acc[1]=MF(AF[0],B1,acc[1]); acc[2]=MF(AF[1],B1,acc[2]);                             \
    acc[3]=MF(AF[2],B1,acc[3]); acc[4]=MF(AF[3],B1,acc[4]);                             \
    acc[2]=MF(AF[0],B2,acc[2]); acc[3]=MF(AF[1],B2,acc[3]);                             \
    acc[4]=MF(AF[2],B2,acc[4]); acc[5]=MF(AF[3],B2,acc[5]);                             \
    acc[3]=MF(AF[0],B3,acc[3]); acc[4]=MF(AF[1],B3,acc[4]);                             \
    acc[5]=MF(AF[2],B3,acc[5]); acc[6]=MF(AF[3],B3,acc[6]);                             \
} while (0)

// per-lane chunk loads: 4 b128 x-floats (own A fragment), 4 dwordx4 B limbs
#define LOADX(X0, X1, X2, X3, c) do {                            \
    const float* _xp = xrow + (c) * KC;                          \
    X0 = *(const float4*)(_xp);                                  \
    X1 = *(const float4*)(_xp + 4);                              \
    X2 = *(const float4*)(_xp + 8);                              \
    X3 = *(const float4*)(_xp + 12);                             \
} while (0)

#define LOADBR(B0, B1, B2, B3, c) do {                           \
    const int* _bp = bbase + (c) * 16;                           \
    B0 = *(const v4i*)(_bp);                                     \
    B1 = *(const v4i*)(_bp + 1 * (DIM / 4));                     \
    B2 = *(const v4i*)(_bp + 2 * (DIM / 4));                     \
    B3 = *(const v4i*)(_bp + 3 * (DIM / 4));                     \
} while (0)

// ---------------- main: barrier-free i8-MFMA router, in-register decomp ----------------
__global__ __launch_bounds__(256, 2) void router_i8_kernel(
    const float* __restrict__ x, const double* __restrict__ pinv,
    const int* __restrict__ plimb, float* __restrict__ out)
{
    __shared__ float  logits[TB][NEXP];    // 4 KiB
    __shared__ double xinv_lds[TB];
    __shared__ double pinv_lds[NEXP];

    const int tid  = threadIdx.x;
    const int lane = tid & 63;
    const int w    = tid >> 6;            // wave 0..3 = expert tile
    const int tok0 = blockIdx.x * TB;

    const int etile = w;
    const int arow  = lane & 15;          // token-within-tile / B-col label
    const int akg   = lane >> 4;          // quarter-wave k-group

    // lane's own A floats: token arow, k in [c*64 + akg*16, +16)
    const float* xrow = x + (size_t)(tok0 + arow) * DIM + akg * 16;
    // lane's B limbs: expert col etile*16+arow, k-slot akg*4 dwords
    const int* bbase = plimb + (size_t)(etile * 16 + arow) * NLIMB * (DIM / 4)
                             + akg * 4;

    v4i acc[7];
#pragma unroll
    for (int d = 0; d < 7; ++d) acc[d] = (v4i){0, 0, 0, 0};
    double sumsq = 0.0;

    if (tid < NEXP) pinv_lds[tid] = pinv[tid];

    // decompose the lane's 16 floats -> A fragment (bytes identical to r19 path),
    // accumulate sumsq (sequential order), then 16 class MFMAs
    auto COMPUTE = [&](const float4 q0, const float4 q1,
                       const float4 q2, const float4 q3,
                       const v4i B0, const v4i B1, const v4i B2, const v4i B3) {
        sumsq += (double)q0.x * q0.x + (double)q0.y * q0.y
               + (double)q0.z * q0.z + (double)q0.w * q0.w;
        sumsq += (double)q1.x * q1.x + (double)q1.y * q1.y
               + (double)q1.z * q1.z + (double)q1.w * q1.w;
        sumsq += (double)q2.x * q2.x + (double)q2.y * q2.y
               + (double)q2.z * q2.z + (double)q2.w * q2.w;
        sumsq += (double)q3.x * q3.x + (double)q3.y * q3.y
               + (double)q3.z * q3.z + (double)q3.w * q3.w;
        unsigned u[4][4];
        u[0][0] = (unsigned)(int)rintf(q0.x * XSCALE) + BIAS;
        u[0][1] = (unsigned)(int)rintf(q0.y * XSCALE) + BIAS;
        u[0][2] = (unsigned)(int)rintf(q0.z * XSCALE) + BIAS;
        u[0][3] = (unsigned)(int)rintf(q0.w * XSCALE) + BIAS;
        u[1][0] = (unsigned)(int)rintf(q1.x * XSCALE) + BIAS;
        u[1][1] = (unsigned)(int)rintf(q1.y * XSCALE) + BIAS;
        u[1][2] = (unsigned)(int)rintf(q1.z * XSCALE) + BIAS;
        u[1][3] = (unsigned)(int)rintf(q1.w * XSCALE) + BIAS;
        u[2][0] = (unsigned)(int)rintf(q2.x * XSCALE) + BIAS;
        u[2][1] = (unsigned)(int)rintf(q2.y * XSCALE) + BIAS;
        u[2][2] = (unsigned)(int)rintf(q2.z * XSCALE) + BIAS;
        u[2][3] = (unsigned)(int)rintf(q2.w * XSCALE) + BIAS;
        u[3][0] = (unsigned)(int)rintf(q3.x * XSCALE) + BIAS;
        u[3][1] = (unsigned)(int)rintf(q3.y * XSCALE) + BIAS;
        u[3][2] = (unsigned)(int)rintf(q3.z * XSCALE) + BIAS;
        u[3][3] = (unsigned)(int)rintf(q3.w * XSCALE) + BIAS;
        v4i af[NLIMB];
#pragma unroll
        for (int i = 0; i < NLIMB; ++i) {
#pragma unroll
            for (int g = 0; g < 4; ++g) {
                unsigned d = ((u[g][0] >> (8 * i)) & 255u)
                           | (((u[g][1] >> (8 * i)) & 255u) << 8)
                           | (((u[g][2] >> (8 * i)) & 255u) << 16)
                           | (((u[g][3] >> (8 * i)) & 255u) << 24);
                af[i][g] = (int)(d ^ BIAS);
            }
        }
        BURST16(af, B0, B1, B2, B3);
    };

    // named double buffers (r11-proven hoisting shape; no pinning asm)
    float4 xa0, xa1, xa2, xa3, xb0, xb1, xb2, xb3;
    v4i    ba0, ba1, ba2, ba3, bb0, bb1, bb2, bb3;

    LOADX(xa0, xa1, xa2, xa3, 0);
    LOADBR(ba0, ba1, ba2, ba3, 0);
    for (int c = 0; c < NCHUNK; c += 2) {
        LOADX(xb0, xb1, xb2, xb3, c + 1);
        LOADBR(bb0, bb1, bb2, bb3, c + 1);
        COMPUTE(xa0, xa1, xa2, xa3, ba0, ba1, ba2, ba3);
        if (c + 2 < NCHUNK) {
            LOADX(xa0, xa1, xa2, xa3, c + 2);
            LOADBR(ba0, ba1, ba2, ba3, c + 2);
        }
        COMPUTE(xb0, xb1, xb2, xb3, bb0, bb1, bb2, bb3);
    }

    // ---- xinv: butterfly over the 4 k-quarters (r12-proven; all waves same bits) ----
    sumsq += __shfl_xor(sumsq, 16, 64);
    sumsq += __shfl_xor(sumsq, 32, 64);
    if (akg == 0)
        xinv_lds[arow] = 1.0 / fmax(sqrt(sumsq), 1e-12);

    // ---- i32 layout calibration (r13-proven) ----
    const int ones = 0x01010101;
    v4i onesv = (v4i){ones, ones, ones, ones};
    int rp = arow * ones;
    v4i rowv = (v4i){rp, rp, rp, rp};
    v4i c1 = (v4i){0, 0, 0, 0}, c2 = (v4i){0, 0, 0, 0};
    c1 = __builtin_amdgcn_mfma_i32_16x16x64_i8(rowv, onesv, c1, 0, 0, 0);  // 64*row
    c2 = __builtin_amdgcn_mfma_i32_16x16x64_i8(onesv, rowv, c2, 0, 0, 0);  // 64*col
    __syncthreads();

    // ---- combine classes in f64, scale to cosine logits, cast fp32 ----
#pragma unroll
    for (int i = 0; i < 4; ++i) {
        double S = 0.0;
#pragma unroll
        for (int d = 0; d < 7; ++d)
            S = fma((double)acc[d][i], CWD4[d], S);
        const int tr = c1[i] >> 6;                 // token-within-tile label
        const int ec = c2[i] >> 6;                 // expert-within-16 label
        const int e  = etile * 16 + ec;
        logits[tr][e] = (float)(S * xinv_lds[tr] * pinv_lds[e]);
    }
    __syncthreads();

    // ---- epilogue: np fp32 softmax bit-chain + rank by (w32 desc, idx asc) ----
#pragma unroll 1
    for (int i = 0; i < 4; ++i) {
        const int tl = w * 4 + i;
        const float l32 = logits[tl][lane];

        float m = l32;
#pragma unroll
        for (int d = 1; d < 64; d <<= 1) {
            float o = __shfl_xor(m, d, 64);
            m = fmaxf(m, o);
        }
        const float dd = l32 - m;
        const float e32 = (float)exp((double)dd);

        float r[8];
#pragma unroll
        for (int j = 0; j < 8; ++j) {
            float rj = __shfl(e32, j, 64);
#pragma unroll
            for (int b = 1; b < 8; ++b)
                rj += __shfl(e32, j + 8 * b, 64);
            r[j] = rj;
        }
        const float S = ((r[0] + r[1]) + (r[2] + r[3])) +
                        ((r[4] + r[5]) + (r[6] + r[7]));
        const float wgt = e32 / S;

        int rank = 0;
#pragma unroll 1
        for (int sdist = 1; sdist < 64; ++sdist) {
            float ow = __shfl_xor(wgt, sdist, 64);
            int j = lane ^ sdist;
            rank += (ow > wgt) || (ow == wgt && j < lane);
        }

        if (rank < TOPK) {
            const int tok = tok0 + tl;
            out[tok * TOPK + rank] = wgt;
            out[NTOK * TOPK + tok * TOPK + rank] = (float)lane;
        }
    }
}

// ---------------- fallback: proven r12 f64-MFMA kernel (ws too small) ----------------
__global__ __launch_bounds__(256, 2) void router_f64_kernel(
    const float* __restrict__ x, const float* __restrict__ proto,
    float* __restrict__ out)
{
    __shared__ float  logits[TB][NEXP];
    __shared__ double xinv_lds[TB];
    __shared__ double pinv_lds[NEXP];

    const int tid  = threadIdx.x;
    const int lane = tid & 63;
    const int w    = tid >> 6;
    const int tok0 = blockIdx.x * TB;
    const int etile = w;
    const int arow  = lane & 15;
    const int akg   = lane >> 4;
    const int kbase = akg * 8;

    v4d acc0 = {0., 0., 0., 0.}, acc1 = {0., 0., 0., 0.};
    v4d acc2 = {0., 0., 0., 0.}, acc3 = {0., 0., 0., 0.};
    double sumsq = 0.0, psq = 0.0;

    const float* xrow = x     + (size_t)(tok0 + arow)       * DIM + kbase;
    const float* prow = proto + (size_t)(etile * 16 + arow) * DIM + kbase;

    float4 xa0, xa1, pa0, pa1, xb0, xb1, pb0, pb1;

#define FLOADSET(X0, X1, P0, P1, c) do {                            \
    const float* _xp = xrow + (c) * 32;                             \
    const float* _pp = prow + (c) * 32;                             \
    X0 = *(const float4*)(_xp);  X1 = *(const float4*)(_xp + 4);    \
    P0 = *(const float4*)(_pp);  P1 = *(const float4*)(_pp + 4);    \
    } while (0)
#define FNORMQ(A, B) do {                                           \
    double a0 = (double)A.x, a1 = (double)A.y,                      \
           a2 = (double)A.z, a3 = (double)A.w;                      \
    double u0 = (double)B.x, u1 = (double)B.y,                      \
           u2 = (double)B.z, u3 = (double)B.w;                      \
    sumsq += a0*a0 + a1*a1 + a2*a2 + a3*a3;                         \
    psq   += u0*u0 + u1*u1 + u2*u2 + u3*u3;                         \
    } while (0)
#define FCOMPUTE(X0, X1, P0, P1) do {                               \
    FNORMQ(X0, P0); FNORMQ(X1, P1);                                 \
    acc0 = __builtin_amdgcn_mfma_f64_16x16x4f64((double)X0.x, (double)P0.x, acc0, 0, 0, 0); \
    acc1 = __builtin_amdgcn_mfma_f64_16x16x4f64((double)X0.y, (double)P0.y, acc1, 0, 0, 0); \
    acc2 = __builtin_amdgcn_mfma_f64_16x16x4f64((double)X0.z, (double)P0.z, acc2, 0, 0, 0); \
    acc3 = __builtin_amdgcn_mfma_f64_16x16x4f64((double)X0.w, (double)P0.w, acc3, 0, 0, 0); \
    acc0 = __builtin_amdgcn_mfma_f64_16x16x4f64((double)X1.x, (double)P1.x, acc0, 0, 0, 0); \
    acc1 = __builtin_amdgcn_mfma_f64_16x16x4f64((double)X1.y, (double)P1.y, acc1, 0, 0, 0); \
    acc2 = __builtin_amdgcn_mfma_f64_16x16x4f64((double)X1.z, (double)P1.z, acc2, 0, 0, 0); \
    acc3 = __builtin_amdgcn_mfma_f64_16x16x4f64((double)X1.w, (double)P1.w, acc3, 0, 0, 0); \
    } while (0)

    FLOADSET(xa0, xa1, pa0, pa1, 0);
    for (int c = 0; c < 64; c += 2) {
        FLOADSET(xb0, xb1, pb0, pb1, c + 1);
        FCOMPUTE(xa0, xa1, pa0, pa1);
        if (c + 2 < 64) FLOADSET(xa0, xa1, pa0, pa1, c + 2);
        FCOMPUTE(xb0, xb1, pb0, pb1);
    }
    const v4d acc = (acc0 + acc1) + (acc2 + acc3);

    sumsq += __shfl_xor(sumsq, 16, 64);
    sumsq += __shfl_xor(sumsq, 32, 64);
    psq   += __shfl_xor(psq, 16, 64);
    psq   += __shfl_xor(psq, 32, 64);
    if (akg == 0) {
        xinv_lds[arow]              = 1.0 / fmax(sqrt(sumsq), 1e-12);
        pinv_lds[etile * 16 + arow] = 1.0 / fmax(sqrt(psq), 1e-12);
    }
    v4d c1 = {0., 0., 0., 0.}, c2 = {0., 0., 0., 0.};
    c1 = __builtin_amdgcn_mfma_f64_16x16x4f64((double)arow, 1.0, c1, 0, 0, 0);
    c2 = __builtin_amdgcn_mfma_f64_16x16x4f64(1.0, (double)arow, c2, 0, 0, 0);
    __syncthreads();
#pragma unroll
    for (int i = 0; i < 4; ++i) {
        const int tr = (int)(c1[i] * 0.25);
        const int ec = (int)(c2[i] * 0.25);
        const int e  = etile * 16 + ec;
        logits[tr][e] = (float)(acc[i] * xinv_lds[tr] * pinv_lds[e]);
    }
    __syncthreads();
#pragma unroll 1
    for (int i = 0; i < 4; ++i) {
        const int tl = w * 4 + i;
        const float l32 = logits[tl][lane];
        float m = l32;
#pragma unroll
        for (int d = 1; d < 64; d <<= 1) {
            float o = __shfl_xor(m, d, 64);
            m = fmaxf(m, o);
        }
        const float dd = l32 - m;
        const float e32 = (float)exp((double)dd);
        float r[8];
#pragma unroll
        for (int j = 0; j < 8; ++j) {
            float rj = __shfl(e32, j, 64);
#pragma unroll
            for (int b = 1; b < 8; ++b)
                rj += __shfl(e32, j + 8 * b, 64);
            r[j] = rj;
        }
        const float S = ((r[0] + r[1]) + (r[2] + r[3])) +
                        ((r[4] + r[5]) + (r[6] + r[7]));
        const float wgt = e32 / S;
        int rank = 0;
#pragma unroll 1
        for (int sdist = 1; sdist < 64; ++sdist) {
            float ow = __shfl_xor(wgt, sdist, 64);
            int j = lane ^ sdist;
            rank += (ow > wgt) || (ow == wgt && j < lane);
        }
        if (rank < TOPK) {
            const int tok = tok0 + tl;
            out[tok * TOPK + rank] = wgt;
            out[NTOK * TOPK + tok * TOPK + rank] = (float)lane;
        }
    }
}

extern "C" void kernel_launch(void* const* d_in, const int* in_sizes, int n_in,
                              void* d_out, int out_size, void* d_ws, size_t ws_size,
                              hipStream_t stream) {
    const float* x     = (const float*)d_in[0];
    const float* proto = (const float*)d_in[1];
    float* out         = (float*)d_out;
    (void)in_sizes; (void)n_in; (void)out_size;

    if (ws_size >= WS_NEEDED) {
        double* pinv = (double*)d_ws;
        int*    plimb = (int*)((char*)d_ws + 512);
        proto_prep_kernel<<<NEXP, 64, 0, stream>>>(proto, pinv, plimb);
        router_i8_kernel<<<NTOK / TB, 256, 0, stream>>>(x, pinv, plimb, out);
    } else {
        router_f64_kernel<<<NTOK / TB, 256, 0, stream>>>(x, proto, out);
    }
}

// Round 23
// 98.231 us; speedup vs baseline: 1.5167x; 1.5167x over previous
//
#include <hip/hip_runtime.h>
#include <math.h>

#define NTOK   16384
#define DIM    2048
#define NEXP   64
#define TOPK   8
#define TB     16          // tokens per block -> grid 1024 (4 blocks/CU)
#define KC     64
#define PKC    128         // K per phase (2 x 64-k sub-chunks)
#define NPHASE (DIM / PKC) // 16
#define XLS    20          // xl row stride (dwords): 80B rows, 16B-aligned reads
#define NLIMB  4

typedef int    v4i __attribute__((ext_vector_type(4)));
typedef double v4d __attribute__((ext_vector_type(4)));

// ws layout: [0,512) pinv (64 f64); [512, 512+524288) proto limb dwords
#define WS_NEEDED (512 + (size_t)NEXP * NLIMB * (DIM / 4) * 4)

#define XSCALE 134217728.0f     // 2^27 : x digits; residual <= 2^-28
#define PSCALE 8589934592.0f    // 2^33 : p digits; residual <= 2^-34
#define BIAS   0x80808080u      // per-byte +128 bias (carry-free digits)

// class-combine weights 2^(8d-60), d=0..6
__device__ __constant__ double CWD4[7] = {
    8.673617379884035e-19, 2.220446049250313e-16, 5.684341886080802e-14,
    1.4551915228366852e-11, 3.725290298461914e-09, 9.5367431640625e-07,
    2.44140625e-04};

// ---------------- pre-kernel: pinv (f64) + proto 4-limb radix-256 decomposition ----------------
__global__ __launch_bounds__(64) void proto_prep_kernel(
    const float* __restrict__ proto, double* __restrict__ pinv,
    int* __restrict__ plimb)
{
    const int e = blockIdx.x, t = threadIdx.x;
    const float* row = proto + (size_t)e * DIM;
    const int k0 = t * 32;
    double s = 0.0;
#pragma unroll
    for (int g = 0; g < 8; ++g) {
        unsigned pk0 = 0, pk1 = 0, pk2 = 0, pk3 = 0;
#pragma unroll
        for (int b = 0; b < 4; ++b) {
            float f = row[k0 + g * 4 + b];
            s += (double)f * (double)f;
            int u = (int)rintf(f * PSCALE);       // exact: pow2 scale + rndne
            unsigned ub = (unsigned)u + BIAS;     // carry-free biased digits
            pk0 |= ( ub        & 255u) << (8 * b);
            pk1 |= ((ub >>  8) & 255u) << (8 * b);
            pk2 |= ((ub >> 16) & 255u) << (8 * b);
            pk3 |= ( ub >> 24        ) << (8 * b);
        }
        const int dw = (k0 + g * 4) >> 2;
        plimb[(e * NLIMB + 0) * (DIM / 4) + dw] = (int)(pk0 ^ BIAS);
        plimb[(e * NLIMB + 1) * (DIM / 4) + dw] = (int)(pk1 ^ BIAS);
        plimb[(e * NLIMB + 2) * (DIM / 4) + dw] = (int)(pk2 ^ BIAS);
        plimb[(e * NLIMB + 3) * (DIM / 4) + dw] = (int)(pk3 ^ BIAS);
    }
#pragma unroll
    for (int d = 1; d < 64; d <<= 1)
        s += __shfl_xor(s, d, 64);
    if (t == 0)
        pinv[e] = 1.0 / fmax(sqrt(s), 1e-12);
}

#define MF(A, B, C) __builtin_amdgcn_mfma_i32_16x16x64_i8(A, B, C, 0, 0, 0)

// 16 class MFMAs (4x4 limbs, class d=i+j in 0..6), j-major (r18-verified)
#define BURST16(AF, B0, B1, B2, B3) do {                                                \
    acc[0]=MF(AF[0],B0,acc[0]); acc[1]=MF(AF[1],B0,acc[1]);                             \
    acc[2]=MF(AF[2],B0,acc[2]); acc[3]=MF(AF[3],B0,acc[3]);                             \
    acc[1]=MF(AF[0],B1,acc[1]); acc[2]=MF(AF[1],B1,acc[2]);                             \
    acc[3]=MF(AF[2],B1,acc[3]); acc[4]=MF(AF[3],B1,acc[4]);                             \
    acc[2]=MF(AF[0],B2,acc[2]); acc[3]=MF(AF[1],B2,acc[3]);                             \
    acc[4]=MF(AF[2],B2,acc[4]); acc[5]=MF(AF[3],B2,acc[5]);                             \
    acc[3]=MF(AF[0],B3,acc[3]); acc[4]=MF(AF[1],B3,acc[4]);                             \
    acc[5]=MF(AF[2],B3,acc[5]); acc[6]=MF(AF[3],B3,acc[6]);                             \
} while (0)

// load both sub-chunks' A limbs: 8x ds_read_b128
#define LOADAF8(cur) do {                                        \
    af0[0] = *(const v4i*)&xl[cur][0][0][arow][akg * 4];         \
    af0[1] = *(const v4i*)&xl[cur][0][1][arow][akg * 4];         \
    af0[2] = *(const v4i*)&xl[cur][0][2][arow][akg * 4];         \
    af0[3] = *(const v4i*)&xl[cur][0][3][arow][akg * 4];         \
    af1[0] = *(const v4i*)&xl[cur][1][0][arow][akg * 4];         \
    af1[1] = *(const v4i*)&xl[cur][1][1][arow][akg * 4];         \
    af1[2] = *(const v4i*)&xl[cur][1][2][arow][akg * 4];         \
    af1[3] = *(const v4i*)&xl[cur][1][3][arow][akg * 4];         \
} while (0)

// load both sub-chunks' B limbs for phase (c): 8x global dwordx4
#define LOADB8(c) do {                                           \
    const int* _bp = bbase + (c) * 32;                           \
    bf0 = *(const v4i*)(_bp);                                    \
    bf1 = *(const v4i*)(_bp + 1 * (DIM / 4));                    \
    bf2 = *(const v4i*)(_bp + 2 * (DIM / 4));                    \
    bf3 = *(const v4i*)(_bp + 3 * (DIM / 4));                    \
    bf4 = *(const v4i*)(_bp + 16);                               \
    bf5 = *(const v4i*)(_bp + 16 + 1 * (DIM / 4));               \
    bf6 = *(const v4i*)(_bp + 16 + 2 * (DIM / 4));               \
    bf7 = *(const v4i*)(_bp + 16 + 3 * (DIM / 4));               \
} while (0)

// ---------------- main: i8-MFMA router, 2-chunk phases, v_perm decomp ----------------
__global__ __launch_bounds__(256, 2) void router_i8_kernel(
    const float* __restrict__ x, const double* __restrict__ pinv,
    const int* __restrict__ plimb, float* __restrict__ out)
{
    __shared__ __align__(16) int xl[2][2][NLIMB][TB][XLS];  // 20480 B, dbuf x 2 subchunks
    __shared__ float  logits[TB][NEXP];                     // 4 KiB
    __shared__ double xinv_lds[TB];
    __shared__ double pinv_lds[NEXP];

    const int tid  = threadIdx.x;
    const int lane = tid & 63;
    const int w    = tid >> 6;            // wave = expert tile [16w,16w+16)
    const int tok0 = blockIdx.x * TB;

    // decomp role: 8 floats per thread covers the 16x128 phase exactly once
    const int td = tid >> 4;              // token 0..15
    const int dw = tid & 15;              // dword group within sub-chunk
    const float* xsrc = x + (size_t)(tok0 + td) * DIM + dw * 4;

    // MFMA role
    const int arow = lane & 15;           // A-row / B-col label
    const int akg  = lane >> 4;           // quarter-wave k-group
    const int ecol = w * 16 + arow;
    const int* bbase = plimb + (size_t)ecol * NLIMB * (DIM / 4) + akg * 4;

    v4i acc[7];
#pragma unroll
    for (int d = 0; d < 7; ++d) acc[d] = (v4i){0, 0, 0, 0};
    double sumsq = 0.0;

    if (tid < NEXP) pinv_lds[tid] = pinv[tid];

    // pack one 4-float group -> 4 limb dwords via v_perm 4x4 byte transpose.
    // Bytes identical to the r19 shift/mask path (limb i byte g = byte i of u_g).
    auto pack4 = [&](const float4 q, int buf, int sub) {
        sumsq += (double)q.x * q.x + (double)q.y * q.y
               + (double)q.z * q.z + (double)q.w * q.w;
        unsigned u0 = (unsigned)(int)rintf(q.x * XSCALE) + BIAS;
        unsigned u1 = (unsigned)(int)rintf(q.y * XSCALE) + BIAS;
        unsigned u2 = (unsigned)(int)rintf(q.z * XSCALE) + BIAS;
        unsigned u3 = (unsigned)(int)rintf(q.w * XSCALE) + BIAS;
        unsigned t01l = __builtin_amdgcn_perm(u1, u0, 0x05010400u); // [u0b0,u1b0,u0b1,u1b1]
        unsigned t23l = __builtin_amdgcn_perm(u3, u2, 0x05010400u);
        unsigned t01h = __builtin_amdgcn_perm(u1, u0, 0x07030602u); // [u0b2,u1b2,u0b3,u1b3]
        unsigned t23h = __builtin_amdgcn_perm(u3, u2, 0x07030602u);
        xl[buf][sub][0][td][dw] = (int)(__builtin_amdgcn_perm(t23l, t01l, 0x05040100u) ^ BIAS);
        xl[buf][sub][1][td][dw] = (int)(__builtin_amdgcn_perm(t23l, t01l, 0x07060302u) ^ BIAS);
        xl[buf][sub][2][td][dw] = (int)(__builtin_amdgcn_perm(t23h, t01h, 0x05040100u) ^ BIAS);
        xl[buf][sub][3][td][dw] = (int)(__builtin_amdgcn_perm(t23h, t01h, 0x07060302u) ^ BIAS);
    };
    auto decomp_store = [&](const float4 q0, const float4 q1, int buf) {
        pack4(q0, buf, 0);
        pack4(q1, buf, 1);
    };

    // named B-limb registers, single-buffered (r17/r18 pinned pattern)
    v4i bf0, bf1, bf2, bf3, bf4, bf5, bf6, bf7;

    // ---- prologue: B(0) in flight; phase 0 decomposed; phase-1 floats in regs ----
    LOADB8(0);
    float4 xv0 = *(const float4*)(xsrc);
    float4 xv1 = *(const float4*)(xsrc + 64);
    decomp_store(xv0, xv1, 0);
    xv0 = *(const float4*)(xsrc + PKC);
    xv1 = *(const float4*)(xsrc + PKC + 64);
    asm volatile("s_waitcnt lgkmcnt(0)" ::: "memory");   // xl(0)+pinv writes landed
    __builtin_amdgcn_sched_barrier(0);
    __builtin_amdgcn_s_barrier();

    // ---- main loop: 16 phases, pinned; raw barrier (B loads fly across) ----
    for (int c = 0; c < NPHASE; ++c) {
        const int cur = c & 1;

        v4i af0[NLIMB], af1[NLIMB];
        LOADAF8(cur);                                    // ds_read_b128 x8
        if (c + 1 < NPHASE) {
            decomp_store(xv0, xv1, cur ^ 1);             // VALU covers af latency
            if (c + 2 < NPHASE) {
                xv0 = *(const float4*)(xsrc + (c + 2) * PKC);
                xv1 = *(const float4*)(xsrc + (c + 2) * PKC + 64);
            }
        }
        asm volatile("s_waitcnt lgkmcnt(0)" ::: "memory"); // af ready, writes landed
        __builtin_amdgcn_sched_barrier(0);               // rule #18: pin MFMA below

        __builtin_amdgcn_s_setprio(1);
        BURST16(af0, bf0, bf1, bf2, bf3);                // sub-chunk 0
        BURST16(af1, bf4, bf5, bf6, bf7);                // sub-chunk 1
        __builtin_amdgcn_s_setprio(0);
        __builtin_amdgcn_sched_barrier(0);               // pin LOADB after BURST

        if (c + 1 < NPHASE) LOADB8(c + 1);               // reuse regs; fly over barrier
        __builtin_amdgcn_sched_barrier(0);
        __builtin_amdgcn_s_barrier();                    // raw: no vmcnt drain
    }

    // ---- xinv: butterfly across the 16 threads sharing a token ----
    sumsq += __shfl_xor(sumsq, 1, 16);
    sumsq += __shfl_xor(sumsq, 2, 16);
    sumsq += __shfl_xor(sumsq, 4, 16);
    sumsq += __shfl_xor(sumsq, 8, 16);
    if (dw == 0)
        xinv_lds[td] = 1.0 / fmax(sqrt(sumsq), 1e-12);

    // ---- i32 layout calibration (r13-proven) ----
    const int ones = 0x01010101;
    v4i onesv = (v4i){ones, ones, ones, ones};
    int rp = arow * ones;
    v4i rowv = (v4i){rp, rp, rp, rp};
    v4i c1 = (v4i){0, 0, 0, 0}, c2 = (v4i){0, 0, 0, 0};
    c1 = __builtin_amdgcn_mfma_i32_16x16x64_i8(rowv, onesv, c1, 0, 0, 0);  // 64*row
    c2 = __builtin_amdgcn_mfma_i32_16x16x64_i8(onesv, rowv, c2, 0, 0, 0);  // 64*col
    __syncthreads();

    // ---- combine classes in f64, scale to cosine logits, cast fp32 ----
#pragma unroll
    for (int i = 0; i < 4; ++i) {
        double S = 0.0;
#pragma unroll
        for (int d = 0; d < 7; ++d)
            S = fma((double)acc[d][i], CWD4[d], S);
        const int tr = c1[i] >> 6;                 // token-within-tile label
        const int ec = c2[i] >> 6;                 // expert-within-16 label
        const int e  = w * 16 + ec;
        logits[tr][e] = (float)(S * xinv_lds[tr] * pinv_lds[e]);
    }
    __syncthreads();

    // ---- epilogue: np fp32 softmax bit-chain + rank by (w32 desc, idx asc) ----
#pragma unroll 1
    for (int i = 0; i < 4; ++i) {
        const int tl = w * 4 + i;
        const float l32 = logits[tl][lane];

        float m = l32;
#pragma unroll
        for (int d = 1; d < 64; d <<= 1) {
            float o = __shfl_xor(m, d, 64);
            m = fmaxf(m, o);
        }
        const float dd = l32 - m;
        const float e32 = (float)exp((double)dd);

        float r[8];
#pragma unroll
        for (int j = 0; j < 8; ++j) {
            float rj = __shfl(e32, j, 64);
#pragma unroll
            for (int b = 1; b < 8; ++b)
                rj += __shfl(e32, j + 8 * b, 64);
            r[j] = rj;
        }
        const float S = ((r[0] + r[1]) + (r[2] + r[3])) +
                        ((r[4] + r[5]) + (r[6] + r[7]));
        const float wgt = e32 / S;

        int rank = 0;
#pragma unroll 1
        for (int sdist = 1; sdist < 64; ++sdist) {
            float ow = __shfl_xor(wgt, sdist, 64);
            int j = lane ^ sdist;
            rank += (ow > wgt) || (ow == wgt && j < lane);
        }

        if (rank < TOPK) {
            const int tok = tok0 + tl;
            out[tok * TOPK + rank] = wgt;
            out[NTOK * TOPK + tok * TOPK + rank] = (float)lane;
        }
    }
}

// ---------------- fallback: proven r12 f64-MFMA kernel (ws too small) ----------------
__global__ __launch_bounds__(256, 2) void router_f64_kernel(
    const float* __restrict__ x, const float* __restrict__ proto,
    float* __restrict__ out)
{
    __shared__ float  logits[TB][NEXP];
    __shared__ double xinv_lds[TB];
    __shared__ double pinv_lds[NEXP];

    const int tid  = threadIdx.x;
    const int lane = tid & 63;
    const int w    = tid >> 6;
    const int tok0 = blockIdx.x * TB;
    const int etile = w;
    const int arow  = lane & 15;
    const int akg   = lane >> 4;
    const int kbase = akg * 8;

    v4d acc0 = {0., 0., 0., 0.}, acc1 = {0., 0., 0., 0.};
    v4d acc2 = {0., 0., 0., 0.}, acc3 = {0., 0., 0., 0.};
    double sumsq = 0.0, psq = 0.0;

    const float* xrow = x     + (size_t)(tok0 + arow)       * DIM + kbase;
    const float* prow = proto + (size_t)(etile * 16 + arow) * DIM + kbase;

    float4 xa0, xa1, pa0, pa1, xb0, xb1, pb0, pb1;

#define FLOADSET(X0, X1, P0, P1, c) do {                            \
    const float* _xp = xrow + (c) * 32;                             \
    const float* _pp = prow + (c) * 32;                             \
    X0 = *(const float4*)(_xp);  X1 = *(const float4*)(_xp + 4);    \
    P0 = *(const float4*)(_pp);  P1 = *(const float4*)(_pp + 4);    \
    } while (0)
#define FNORMQ(A, B) do {                                           \
    double a0 = (double)A.x, a1 = (double)A.y,                      \
           a2 = (double)A.z, a3 = (double)A.w;                      \
    double u0 = (double)B.x, u1 = (double)B.y,                      \
           u2 = (double)B.z, u3 = (double)B.w;                      \
    sumsq += a0*a0 + a1*a1 + a2*a2 + a3*a3;                         \
    psq   += u0*u0 + u1*u1 + u2*u2 + u3*u3;                         \
    } while (0)
#define FCOMPUTE(X0, X1, P0, P1) do {                               \
    FNORMQ(X0, P0); FNORMQ(X1, P1);                                 \
    acc0 = __builtin_amdgcn_mfma_f64_16x16x4f64((double)X0.x, (double)P0.x, acc0, 0, 0, 0); \
    acc1 = __builtin_amdgcn_mfma_f64_16x16x4f64((double)X0.y, (double)P0.y, acc1, 0, 0, 0); \
    acc2 = __builtin_amdgcn_mfma_f64_16x16x4f64((double)X0.z, (double)P0.z, acc2, 0, 0, 0); \
    acc3 = __builtin_amdgcn_mfma_f64_16x16x4f64((double)X0.w, (double)P0.w, acc3, 0, 0, 0); \
    acc0 = __builtin_amdgcn_mfma_f64_16x16x4f64((double)X1.x, (double)P1.x, acc0, 0, 0, 0); \
    acc1 = __builtin_amdgcn_mfma_f64_16x16x4f64((double)X1.y, (double)P1.y, acc1, 0, 0, 0); \
    acc2 = __builtin_amdgcn_mfma_f64_16x16x4f64((double)X1.z, (double)P1.z, acc2, 0, 0, 0); \
    acc3 = __builtin_amdgcn_mfma_f64_16x16x4f64((double)X1.w, (double)P1.w, acc3, 0, 0, 0); \
    } while (0)

    FLOADSET(xa0, xa1, pa0, pa1, 0);
    for (int c = 0; c < 64; c += 2) {
        FLOADSET(xb0, xb1, pb0, pb1, c + 1);
        FCOMPUTE(xa0, xa1, pa0, pa1);
        if (c + 2 < 64) FLOADSET(xa0, xa1, pa0, pa1, c + 2);
        FCOMPUTE(xb0, xb1, pb0, pb1);
    }
    const v4d acc = (acc0 + acc1) + (acc2 + acc3);

    sumsq += __shfl_xor(sumsq, 16, 64);
    sumsq += __shfl_xor(sumsq, 32, 64);
    psq   += __shfl_xor(psq, 16, 64);
    psq   += __shfl_xor(psq, 32, 64);
    if (akg == 0) {
        xinv_lds[arow]              = 1.0 / fmax(sqrt(sumsq), 1e-12);
        pinv_lds[etile * 16 + arow] = 1.0 / fmax(sqrt(psq), 1e-12);
    }
    v4d c1 = {0., 0., 0., 0.}, c2 = {0., 0., 0., 0.};
    c1 = __builtin_amdgcn_mfma_f64_16x16x4f64((double)arow, 1.0, c1, 0, 0, 0);
    c2 = __builtin_amdgcn_mfma_f64_16x16x4f64(1.0, (double)arow, c2, 0, 0, 0);
    __syncthreads();
#pragma unroll
    for (int i = 0; i < 4; ++i) {
        const int tr = (int)(c1[i] * 0.25);
        const int ec = (int)(c2[i] * 0.25);
        const int e  = etile * 16 + ec;
        logits[tr][e] = (float)(acc[i] * xinv_lds[tr] * pinv_lds[e]);
    }
    __syncthreads();
#pragma unroll 1
    for (int i = 0; i < 4; ++i) {
        const int tl = w * 4 + i;
        const float l32 = logits[tl][lane];
        float m = l32;
#pragma unroll
        for (int d = 1; d < 64; d <<= 1) {
            float o = __shfl_xor(m, d, 64);
            m = fmaxf(m, o);
        }
        const float dd = l32 - m;
        const float e32 = (float)exp((double)dd);
        float r[8];
#pragma unroll
        for (int j = 0; j < 8; ++j) {
            float rj = __shfl(e32, j, 64);
#pragma unroll
            for (int b = 1; b < 8; ++b)
                rj += __shfl(e32, j + 8 * b, 64);
            r[j] = rj;
        }
        const float S = ((r[0] + r[1]) + (r[2] + r[3])) +
                        ((r[4] + r[5]) + (r[6] + r[7]));
        const float wgt = e32 / S;
        int rank = 0;
#pragma unroll 1
        for (int sdist = 1; sdist < 64; ++sdist) {
            float ow = __shfl_xor(wgt, sdist, 64);
            int j = lane ^ sdist;
            rank += (ow > wgt) || (ow == wgt && j < lane);
        }
        if (rank < TOPK) {
            const int tok = tok0 + tl;
            out[tok * TOPK + rank] = wgt;
            out[NTOK * TOPK + tok * TOPK + rank] = (float)lane;
        }
    }
}

extern "C" void kernel_launch(void* const* d_in, const int* in_sizes, int n_in,
                              void* d_out, int out_size, void* d_ws, size_t ws_size,
                              hipStream_t stream) {
    const float* x     = (const float*)d_in[0];
    const float* proto = (const float*)d_in[1];
    float* out         = (float*)d_out;
    (void)in_sizes; (void)n_in; (void)out_size;

    if (ws_size >= WS_NEEDED) {
        double* pinv = (double*)d_ws;
        int*    plimb = (int*)((char*)d_ws + 512);
        proto_prep_kernel<<<NEXP, 64, 0, stream>>>(proto, pinv, plimb);
        router_i8_kernel<<<NTOK / TB, 256, 0, stream>>>(x, pinv, plimb, out);
    } else {
        router_f64_kernel<<<NTOK / TB, 256, 0, stream>>>(x, proto, out);
    }
}